// Round 6
// baseline (229.557 us; speedup 1.0000x reference)
//
#include <hip/hip_runtime.h>
#include <hip/hip_bf16.h>
#include <cstdint>

#define TT   8192
#define KOBS 512
#define HID  2048
#define NOBJ 8
#define NCH  128    // number of time chunks
#define CT   64     // chunk length (TT / NCH)

typedef unsigned short u16;
typedef uint32_t u32;
typedef short bf16x8 __attribute__((ext_vector_type(8)));
typedef float f32x4  __attribute__((ext_vector_type(4)));
typedef unsigned short u16x4 __attribute__((ext_vector_type(4)));

static __device__ __forceinline__ float bf2f(u16 u) {
    union { uint32_t i; float f; } v;
    v.i = ((uint32_t)u) << 16;
    return v.f;
}
static __device__ __forceinline__ u16 f2bf(float f) {
    union { float f; uint32_t i; } v;
    v.f = f;
    uint32_t lsb = (v.i >> 16) & 1u;
    uint32_t r = v.i + 0x7fffu + lsb;   // round-to-nearest-even
    return (u16)(r >> 16);
}

// async global->LDS DMA, 16 bytes per lane (wave-uniform base + lane*16).
static __device__ __forceinline__ void async_ld16(const u16* g, u16* l) {
    __builtin_amdgcn_global_load_lds(
        (const __attribute__((address_space(1))) uint32_t*)g,
        (__attribute__((address_space(3))) uint32_t*)l,
        16, 0, 0);
}

// ---------------------------------------------------------------------------
// Kernel 1: cast + row-interleave the 4 weight matrices
// (row n = 4*h + proj, proj: 0=W_in 1=W_B 2=W_C 3=W_delta);
// A_e[h] = -exp(A_log[h]) * log2(e).
// ---------------------------------------------------------------------------
__global__ void prep_w(const float* __restrict__ Win,
                       const float* __restrict__ WB,
                       const float* __restrict__ WC,
                       const float* __restrict__ Wd,
                       const float* __restrict__ A_log,
                       u16* __restrict__ W_bf,
                       float* __restrict__ A_e)
{
    const int tid0   = blockIdx.x * blockDim.x + threadIdx.x;
    const int stride = gridDim.x * blockDim.x;

    // W: 524,288 groups of 8; 64 consecutive i share row n
    for (int i = tid0; i < 4 * HID * KOBS / 8; i += stride) {
        int n  = i >> 6;
        int k8 = (i & 63) * 8;
        int h  = n >> 2;
        int w  = n & 3;
        const float* src = (w == 0) ? Win : (w == 1) ? WB : (w == 2) ? WC : Wd;
        const float4* s4 = (const float4*)(src + (size_t)h * KOBS + k8);
        float4 a = s4[0], b = s4[1];
        u16x4 o1 = { f2bf(a.x), f2bf(a.y), f2bf(a.z), f2bf(a.w) };
        u16x4 o2 = { f2bf(b.x), f2bf(b.y), f2bf(b.z), f2bf(b.w) };
        *(u16x4*)&W_bf[(size_t)i * 8]     = o1;
        *(u16x4*)&W_bf[(size_t)i * 8 + 4] = o2;
    }

    if (tid0 < HID)
        A_e[tid0] = -__expf(A_log[tid0]) * 1.44269504f;
}

// ---------------------------------------------------------------------------
// Kernel 2: out[t,:] = b_out + x[t,:] @ W_skip.T  (base for atomics)
//           AND x -> bf16 cast (each x element is read exactly once here).
// ---------------------------------------------------------------------------
__launch_bounds__(256)
__global__ void prep_x_out(const float* __restrict__ x,
                           const float* __restrict__ b_out,
                           const float* __restrict__ W_skip,
                           float* __restrict__ out,
                           u16* __restrict__ x_bf)
{
    const int wave = threadIdx.x >> 6;
    const int lane = threadIdx.x & 63;
    const int t0 = (blockIdx.x * 4 + wave) * 4;

    float acc[4][NOBJ];
#pragma unroll
    for (int tt = 0; tt < 4; tt++)
#pragma unroll
        for (int o = 0; o < NOBJ; o++) acc[tt][o] = 0.f;

#pragma unroll
    for (int i = 0; i < 2; i++) {
        const int kv = (i * 64 + lane) * 4;
        float4 w[NOBJ];
#pragma unroll
        for (int o = 0; o < NOBJ; o++)
            w[o] = *(const float4*)(W_skip + (size_t)o * KOBS + kv);
#pragma unroll
        for (int tt = 0; tt < 4; tt++) {
            const size_t off = (size_t)(t0 + tt) * KOBS + kv;
            float4 xv = *(const float4*)(x + off);
            u16x4 xb = { f2bf(xv.x), f2bf(xv.y), f2bf(xv.z), f2bf(xv.w) };
            *(u16x4*)&x_bf[off] = xb;
#pragma unroll
            for (int o = 0; o < NOBJ; o++)
                acc[tt][o] += xv.x * w[o].x + xv.y * w[o].y +
                              xv.z * w[o].z + xv.w * w[o].w;
        }
    }
#pragma unroll
    for (int s = 32; s > 0; s >>= 1)
#pragma unroll
        for (int tt = 0; tt < 4; tt++)
#pragma unroll
            for (int o = 0; o < NOBJ; o++)
                acc[tt][o] += __shfl_xor(acc[tt][o], s, 64);
    if (lane == 0) {
#pragma unroll
        for (int tt = 0; tt < 4; tt++)
#pragma unroll
            for (int o = 0; o < NOBJ; o++)
                out[(size_t)(t0 + tt) * NOBJ + o] = acc[tt][o] + b_out[o];
    }
}

// ---------------------------------------------------------------------------
// Kernel 3: fused GEMM + elementwise + scan-pass1.
// A operand = W rows (n-dim) -> D row (4fq+reg) = n, reg = projection.
// Epilogue: pack {bx, cc, la, 0} u16x4 -> LDS ep[tl][hl] (row stride 37
// slots: bank-pair (5*tl+hl)%16, <=2-way); one ds_write_b64 per (t,h);
// store-back b64-pairs -> b128 global G; pass1 P,S per 64-t half-chunk.
// ---------------------------------------------------------------------------
__launch_bounds__(256)
__global__ void gemm_fused(const u16* __restrict__ x_bf,
                           const u16* __restrict__ W_bf,
                           const float* __restrict__ A_e,
                           u16* __restrict__ G,
                           float* __restrict__ P,
                           float* __restrict__ S)
{
    // union: K-loop staging (16 KB) / epilogue ep[128][37] u16x4 (37888 B)
    __shared__ __align__(16) u16 smem[128 * 37 * 4];
    __shared__ float Ps[256], Ss[256];
    u16* a_s = smem;            // x tile: 128 t-rows x 32 k
    u16* b_s = smem + 4096;     // W tile: 128 n-rows x 32 k

    const int tid  = threadIdx.x;
    const int bm   = blockIdx.x & 63;    // t-tile (two 64-t scan chunks)
    const int bn   = blockIdx.x >> 6;    // channel group (32 h)
    const int m0t  = bm * 128;
    const int n0   = bn * 128;
    const int lane = tid & 63;
    const int wave = tid >> 6;
    const int wn   = (wave & 1) * 64;    // n-dim wave offset
    const int wt   = (wave >> 1) * 64;   // t-dim wave offset
    const int fr   = lane & 15;
    const int fq   = lane >> 4;

    f32x4 acc[4][4];
#pragma unroll
    for (int i = 0; i < 4; i++)
#pragma unroll
        for (int j = 0; j < 4; j++) {
            f32x4 z = {0.f, 0.f, 0.f, 0.f};
            acc[i][j] = z;
        }

    const int srow = tid >> 2;
    const int scg  = (tid & 3) ^ ((srow >> 1) & 3);  // XOR col-group swizzle
    const u16* gA0 = x_bf + (size_t)(m0t + srow) * KOBS + scg * 8;
    const u16* gA1 = gA0 + (size_t)64 * KOBS;
    const u16* gB0 = W_bf + (size_t)(n0 + srow) * KOBS + scg * 8;
    const u16* gB1 = gB0 + (size_t)64 * KOBS;
    u16* lA0 = &a_s[tid * 8];
    u16* lA1 = &a_s[2048 + tid * 8];
    u16* lB0 = &b_s[tid * 8];
    u16* lB1 = &b_s[2048 + tid * 8];

    const int pcg = fq ^ ((fr >> 1) & 3);  // fragment-read swizzled col-group

    for (int kb = 0; kb < KOBS; kb += 32) {
        async_ld16(gA0 + kb, lA0);
        async_ld16(gA1 + kb, lA1);
        async_ld16(gB0 + kb, lB0);
        async_ld16(gB1 + kb, lB1);
        __syncthreads();

        bf16x8 af[4], bfx[4];
#pragma unroll
        for (int i = 0; i < 4; i++)    // A operand = W rows (n-dim)
            af[i] = *(const bf16x8*)&b_s[(wn + i * 16 + fr) * 32 + pcg * 8];
#pragma unroll
        for (int j = 0; j < 4; j++)    // B operand = x rows (t-dim)
            bfx[j] = *(const bf16x8*)&a_s[(wt + j * 16 + fr) * 32 + pcg * 8];

#pragma unroll
        for (int i = 0; i < 4; i++)
#pragma unroll
            for (int j = 0; j < 4; j++)
                acc[i][j] = __builtin_amdgcn_mfma_f32_16x16x32_bf16(
                    af[i], bfx[j], acc[i][j], 0, 0, 0);
        __syncthreads();
    }

    // ---- epilogue: D row = wn + i*16 + 4*fq + reg (reg=proj), col = wt+j*16+fr
    const int hq = wn >> 2;                  // 0 or 16
#pragma unroll
    for (int i = 0; i < 4; i++) {
        const int hl = hq + i * 4 + fq;      // h_local 0..31
        const float ae = A_e[bn * 32 + hl];
#pragma unroll
        for (int j = 0; j < 4; j++) {
            const int tl = wt + j * 16 + fr;
            f32x4 v = acc[i][j];
            float sig = 1.0f / (1.0f + __expf(-v[3]));
            u32 lo = (u32)f2bf(v[0] * v[1]) | ((u32)f2bf(v[2]) << 16);
            u32 hi = (u32)f2bf(sig * ae);
            *(uint2*)&smem[(tl * 37 + hl) * 4] = make_uint2(lo, hi);
        }
    }
    __syncthreads();

    // ---- packed store-back: 4096 slots -> 8 iters of b64-pair -> b128
#pragma unroll
    for (int it = 0; it < 8; it++) {
        const int g   = it * 256 + tid;      // 0..2047
        const int row = g >> 4;
        const int c2  = g & 15;
        uint2 lo = *(const uint2*)&smem[(row * 37 + c2 * 2) * 4];
        uint2 hi = *(const uint2*)&smem[(row * 37 + c2 * 2 + 1) * 4];
        uint4 v = make_uint4(lo.x, lo.y, hi.x, hi.y);
        *(uint4*)(G + ((size_t)(m0t + row) * HID + bn * 32 + c2 * 2) * 4) = v;
    }

    // ---- fused scan pass1: 8 segments x 16 steps, combine per 64-t half
    {
        const int hi  = tid & 31;
        const int seg = tid >> 5;
        float p = 1.f, s = 0.f;
        const int tbase = seg * 16;
#pragma unroll
        for (int t = 0; t < 16; t++) {
            uint2 w = *(const uint2*)&smem[((tbase + t) * 37 + hi) * 4];
            float a  = exp2f(bf2f((u16)(w.y & 0xffff)));
            float bx = bf2f((u16)(w.x & 0xffff));
            s = fmaf(a, s, bx);
            p *= a;
        }
        Ps[seg * 32 + hi] = p;
        Ss[seg * 32 + hi] = s;
        __syncthreads();
        if (tid < 64) {
            const int half = tid >> 5, h2 = tid & 31;
            float pt = 1.f, st = 0.f;
#pragma unroll
            for (int sg = 0; sg < 4; sg++) {
                float ps = Ps[(half * 4 + sg) * 32 + h2];
                float ss = Ss[(half * 4 + sg) * 32 + h2];
                st = fmaf(ps, st, ss);
                pt *= ps;
            }
            P[(size_t)(bm * 2 + half) * HID + bn * 32 + h2] = pt;
            S[(size_t)(bm * 2 + half) * HID + bn * 32 + h2] = st;
        }
    }
}

// ---------------------------------------------------------------------------
// Kernel 4: sequential combine across 128 chunks per channel -> H0[c,h]
// ---------------------------------------------------------------------------
__global__ void scan_combine(const float* __restrict__ P,
                             const float* __restrict__ S,
                             float* __restrict__ H0)
{
    const int h = blockIdx.x * 256 + threadIdx.x;
    float hrun = 0.f;
#pragma unroll 8
    for (int c = 0; c < NCH; c++) {
        H0[c * HID + h] = hrun;
        hrun = fmaf(P[c * HID + h], hrun, S[c * HID + h]);
    }
}

// ---------------------------------------------------------------------------
// Kernel 5: fused pass2 + output GEMM. Block = (chunk c of 64 t, hgroup of
// 256 h), 1024 blocks -> 4 blocks/CU co-resident. Phase 1: scan 64 t with
// 8-deep batched coalesced uint2 loads from packed G; y -> LDS (bf16,
// XOR-swizzled). Phase 2: MFMA (A = W_out bf16 frags from LDS, B = y frags)
// -> atomicAdd into out.
// ---------------------------------------------------------------------------
__launch_bounds__(256)
__global__ void scan_out(const u16* __restrict__ G,
                         const float* __restrict__ H0,
                         const float* __restrict__ W_out,
                         float* __restrict__ out)
{
    __shared__ __align__(16) u16 ybuf[CT * 256];    // 32 KB
    __shared__ __align__(16) u16 wst[8 * 264];      // 4224 B
    const int tid  = threadIdx.x;
    const int c    = blockIdx.x >> 3;    // chunk 0..127
    const int hg   = blockIdx.x & 7;
    const int lane = tid & 63;
    const int wave = tid >> 6;
    const int fr   = lane & 15;
    const int fq   = lane >> 4;

    // stage W_out slice coalesced, as bf16
#pragma unroll
    for (int o = 0; o < 8; o++)
        wst[o * 264 + tid] = f2bf(W_out[(size_t)o * HID + hg * 256 + tid]);

    // phase 1: scan with 8-deep load batching
    const int h = hg * 256 + tid;
    float hrun = H0[c * HID + h];
    size_t base = (size_t)c * CT * HID + h;      // slot index into G
    const int g  = tid >> 3;
    const int lo = tid & 7;
    for (int tb = 0; tb < CT; tb += 8) {
        uint2 wv[8];
#pragma unroll
        for (int q = 0; q < 8; q++)
            wv[q] = *(const uint2*)&G[(base + (size_t)q * HID) * 4];
#pragma unroll
        for (int q = 0; q < 8; q++) {
            float bx = bf2f((u16)(wv[q].x & 0xffff));
            float cc = bf2f((u16)(wv[q].x >> 16));
            float a  = exp2f(bf2f((u16)(wv[q].y & 0xffff)));
            hrun = fmaf(a, hrun, bx);
            const int t = tb + q;
            ybuf[t * 256 + (((g ^ (t & 7)) << 3) | lo)] = f2bf(cc * hrun);
        }
        base += (size_t)8 * HID;
    }
    __syncthreads();

    // build W_out A-frags from LDS: lane fr = o (rows 8..15 zero), k = fq*8+j
    bf16x8 bw[8];
#pragma unroll
    for (int ks = 0; ks < 8; ks++) {
        bf16x8 w = {0, 0, 0, 0, 0, 0, 0, 0};
        if (fr < 8)
            w = *(const bf16x8*)&wst[fr * 264 + ks * 32 + fq * 8];
        bw[ks] = w;
    }

    // phase 2: one 16-t m-tile per wave; D row (4fq+reg) = o, col fr = t
    {
        const int tb = wave * 16;
        const int t  = tb + fr;
        f32x4 acc2 = {0.f, 0.f, 0.f, 0.f};
#pragma unroll
        for (int ks = 0; ks < 8; ks++) {
            const int gg = ks * 4 + fq;
            bf16x8 yv = *(const bf16x8*)
                &ybuf[t * 256 + ((gg ^ (fr & 7)) << 3)];
            acc2 = __builtin_amdgcn_mfma_f32_16x16x32_bf16(bw[ks], yv, acc2,
                                                           0, 0, 0);
        }
        if (fq < 2) {
            const int tg = c * CT + t;
#pragma unroll
            for (int reg = 0; reg < 4; reg++)
                atomicAdd(&out[(size_t)tg * NOBJ + 4 * fq + reg], acc2[reg]);
        }
    }
}

// ---------------------------------------------------------------------------
extern "C" void kernel_launch(void* const* d_in, const int* in_sizes, int n_in,
                              void* d_out, int out_size, void* d_ws, size_t ws_size,
                              hipStream_t stream)
{
    const float* x      = (const float*)d_in[0];
    const float* Win    = (const float*)d_in[1];
    const float* WB     = (const float*)d_in[2];
    const float* WC     = (const float*)d_in[3];
    const float* Wd     = (const float*)d_in[4];
    const float* A_log  = (const float*)d_in[5];
    const float* W_out  = (const float*)d_in[6];
    const float* b_out  = (const float*)d_in[7];
    const float* W_skip = (const float*)d_in[8];
    float* out = (float*)d_out;

    char* ws = (char*)d_ws;
    size_t off = 0;
    auto alloc = [&](size_t bytes) -> void* {
        void* p = (void*)(ws + off);
        off += (bytes + 255) & ~(size_t)255;
        return p;
    };

    u16*   x_bf = (u16*)  alloc((size_t)TT * KOBS * 2);        //   8.4 MB
    u16*   W_bf = (u16*)  alloc((size_t)4 * HID * KOBS * 2);   //   8.4 MB
    float* A_e  = (float*)alloc((size_t)HID * 4);
    u16*   G    = (u16*)  alloc((size_t)TT * HID * 8);         // 134.2 MB
    float* P    = (float*)alloc((size_t)NCH * HID * 4);        //   1 MB
    float* S    = (float*)alloc((size_t)NCH * HID * 4);        //   1 MB
    float* H0   = (float*)alloc((size_t)NCH * HID * 4);        //   1 MB
    (void)ws_size; (void)in_sizes; (void)n_in; (void)out_size;

    prep_w<<<2048, 256, 0, stream>>>(Win, WB, WC, Wd, A_log, W_bf, A_e);
    prep_x_out<<<512, 256, 0, stream>>>(x, b_out, W_skip, out, x_bf);
    gemm_fused<<<4096, 256, 0, stream>>>(x_bf, W_bf, A_e, G, P, S);
    scan_combine<<<8, 256, 0, stream>>>(P, S, H0);
    scan_out<<<1024, 256, 0, stream>>>(G, H0, W_out, out);
}

// Round 7
// 217.322 us; speedup vs baseline: 1.0563x; 1.0563x over previous
//
#include <hip/hip_runtime.h>
#include <hip/hip_bf16.h>
#include <cstdint>

#define TT   8192
#define KOBS 512
#define HID  2048
#define NOBJ 8
#define NCH  64     // number of scan chunks (= gemm t-tiles)
#define CT   128    // chunk length (TT / NCH)

typedef unsigned short u16;
typedef uint32_t u32;
typedef short bf16x8 __attribute__((ext_vector_type(8)));
typedef float f32x4  __attribute__((ext_vector_type(4)));
typedef unsigned short u16x4 __attribute__((ext_vector_type(4)));

static __device__ __forceinline__ float bf2f(u16 u) {
    union { uint32_t i; float f; } v;
    v.i = ((uint32_t)u) << 16;
    return v.f;
}
static __device__ __forceinline__ u16 f2bf(float f) {
    union { float f; uint32_t i; } v;
    v.f = f;
    uint32_t lsb = (v.i >> 16) & 1u;
    uint32_t r = v.i + 0x7fffu + lsb;   // round-to-nearest-even
    return (u16)(r >> 16);
}

// async global->LDS DMA, 16 bytes per lane (wave-uniform base + lane*16).
static __device__ __forceinline__ void async_ld16(const u16* g, u16* l) {
    __builtin_amdgcn_global_load_lds(
        (const __attribute__((address_space(1))) uint32_t*)g,
        (__attribute__((address_space(3))) uint32_t*)l,
        16, 0, 0);
}

// ---------------------------------------------------------------------------
// Kernel 1: cast + row-interleave the 4 weight matrices
// (row n = 4*h + proj, proj: 0=W_in 1=W_B 2=W_C 3=W_delta);
// A_e[h] = -exp(A_log[h]) * log2(e).
// ---------------------------------------------------------------------------
__global__ void prep_w(const float* __restrict__ Win,
                       const float* __restrict__ WB,
                       const float* __restrict__ WC,
                       const float* __restrict__ Wd,
                       const float* __restrict__ A_log,
                       u16* __restrict__ W_bf,
                       float* __restrict__ A_e)
{
    const int tid0   = blockIdx.x * blockDim.x + threadIdx.x;
    const int stride = gridDim.x * blockDim.x;

    for (int i = tid0; i < 4 * HID * KOBS / 8; i += stride) {
        int n  = i >> 6;
        int k8 = (i & 63) * 8;
        int h  = n >> 2;
        int w  = n & 3;
        const float* src = (w == 0) ? Win : (w == 1) ? WB : (w == 2) ? WC : Wd;
        const float4* s4 = (const float4*)(src + (size_t)h * KOBS + k8);
        float4 a = s4[0], b = s4[1];
        u16x4 o1 = { f2bf(a.x), f2bf(a.y), f2bf(a.z), f2bf(a.w) };
        u16x4 o2 = { f2bf(b.x), f2bf(b.y), f2bf(b.z), f2bf(b.w) };
        *(u16x4*)&W_bf[(size_t)i * 8]     = o1;
        *(u16x4*)&W_bf[(size_t)i * 8 + 4] = o2;
    }

    if (tid0 < HID)
        A_e[tid0] = -__expf(A_log[tid0]) * 1.44269504f;
}

// ---------------------------------------------------------------------------
// Kernel 2: out[t,:] = b_out + x[t,:] @ W_skip.T  (base for atomics)
//           AND x -> bf16 cast (each x element read exactly once here).
// ---------------------------------------------------------------------------
__launch_bounds__(256)
__global__ void prep_x_out(const float* __restrict__ x,
                           const float* __restrict__ b_out,
                           const float* __restrict__ W_skip,
                           float* __restrict__ out,
                           u16* __restrict__ x_bf)
{
    const int wave = threadIdx.x >> 6;
    const int lane = threadIdx.x & 63;
    const int t0 = (blockIdx.x * 4 + wave) * 4;

    float acc[4][NOBJ];
#pragma unroll
    for (int tt = 0; tt < 4; tt++)
#pragma unroll
        for (int o = 0; o < NOBJ; o++) acc[tt][o] = 0.f;

#pragma unroll
    for (int i = 0; i < 2; i++) {
        const int kv = (i * 64 + lane) * 4;
        float4 w[NOBJ];
#pragma unroll
        for (int o = 0; o < NOBJ; o++)
            w[o] = *(const float4*)(W_skip + (size_t)o * KOBS + kv);
#pragma unroll
        for (int tt = 0; tt < 4; tt++) {
            const size_t off = (size_t)(t0 + tt) * KOBS + kv;
            float4 xv = *(const float4*)(x + off);
            u16x4 xb = { f2bf(xv.x), f2bf(xv.y), f2bf(xv.z), f2bf(xv.w) };
            *(u16x4*)&x_bf[off] = xb;
#pragma unroll
            for (int o = 0; o < NOBJ; o++)
                acc[tt][o] += xv.x * w[o].x + xv.y * w[o].y +
                              xv.z * w[o].z + xv.w * w[o].w;
        }
    }
#pragma unroll
    for (int s = 32; s > 0; s >>= 1)
#pragma unroll
        for (int tt = 0; tt < 4; tt++)
#pragma unroll
            for (int o = 0; o < NOBJ; o++)
                acc[tt][o] += __shfl_xor(acc[tt][o], s, 64);
    if (lane == 0) {
#pragma unroll
        for (int tt = 0; tt < 4; tt++)
#pragma unroll
            for (int o = 0; o < NOBJ; o++)
                out[(size_t)(t0 + tt) * NOBJ + o] = acc[tt][o] + b_out[o];
    }
}

// ---------------------------------------------------------------------------
// Kernel 3: fused GEMM + elementwise + FULL in-LDS chunk scan.
// K-loop/epilogue-transpose identical to the proven round-5 kernel
// (84 VGPR / 32.8 KB LDS). Then, entirely in LDS:
//   pass 1: per-(seg,h) totals (8 segs x 16 t)
//   prefix: tid<32 converts Ps/Ss to seg prefixes in place; writes chunk P,S
//   pass 2: recompute seg scan; emit YB = C*s_t, YC = C*r_t (chunk-local
//           scan and prefix-product) overwriting planes 0/2
//   store-back planes 0/2 (67 MB total, vs 100 MB before).
// Downstream y(t) = YB + YC*h0[chunk] is fully parallel — no serial pass 2.
// ---------------------------------------------------------------------------
__launch_bounds__(256)
__global__ void gemm_fused(const u16* __restrict__ x_bf,
                           const u16* __restrict__ W_bf,
                           const float* __restrict__ A_e,
                           u16* __restrict__ YB,
                           u16* __restrict__ YC,
                           float* __restrict__ P,
                           float* __restrict__ S)
{
    // union: K-loop staging (16 KB) / epilogue transpose buffer (30 KB)
    __shared__ __align__(16) u16 smem[3 * 128 * 40];   // 30720 B
    __shared__ float Ps[256], Ss[256];                 //  2 KB
    u16* a_s = smem;            // x tile: 128 t-rows x 32 k
    u16* b_s = smem + 4096;     // W tile: 128 n-rows x 32 k

    const int tid  = threadIdx.x;
    const int bm   = blockIdx.x & 63;    // t-chunk (== scan chunk c)
    const int bn   = blockIdx.x >> 6;    // channel group (32 h)
    const int m0t  = bm * 128;
    const int n0   = bn * 128;
    const int lane = tid & 63;
    const int wave = tid >> 6;
    const int wn   = (wave & 1) * 64;    // n-dim wave offset
    const int wt   = (wave >> 1) * 64;   // t-dim wave offset
    const int fr   = lane & 15;
    const int fq   = lane >> 4;

    f32x4 acc[4][4];
#pragma unroll
    for (int i = 0; i < 4; i++)
#pragma unroll
        for (int j = 0; j < 4; j++) {
            f32x4 z = {0.f, 0.f, 0.f, 0.f};
            acc[i][j] = z;
        }

    const int srow = tid >> 2;                       // 0..63
    const int scg  = (tid & 3) ^ ((srow >> 1) & 3);  // XOR col-group swizzle
    const u16* gA0 = x_bf + (size_t)(m0t + srow) * KOBS + scg * 8;
    const u16* gA1 = gA0 + (size_t)64 * KOBS;
    const u16* gB0 = W_bf + (size_t)(n0 + srow) * KOBS + scg * 8;
    const u16* gB1 = gB0 + (size_t)64 * KOBS;
    u16* lA0 = &a_s[tid * 8];
    u16* lA1 = &a_s[2048 + tid * 8];
    u16* lB0 = &b_s[tid * 8];
    u16* lB1 = &b_s[2048 + tid * 8];

    const int pcg = fq ^ ((fr >> 1) & 3);  // fragment-read swizzled col-group

    for (int kb = 0; kb < KOBS; kb += 32) {
        async_ld16(gA0 + kb, lA0);
        async_ld16(gA1 + kb, lA1);
        async_ld16(gB0 + kb, lB0);
        async_ld16(gB1 + kb, lB1);
        __syncthreads();

        bf16x8 af[4], bfx[4];
#pragma unroll
        for (int i = 0; i < 4; i++)    // A operand = W rows (n-dim)
            af[i] = *(const bf16x8*)&b_s[(wn + i * 16 + fr) * 32 + pcg * 8];
#pragma unroll
        for (int j = 0; j < 4; j++)    // B operand = x rows (t-dim)
            bfx[j] = *(const bf16x8*)&a_s[(wt + j * 16 + fr) * 32 + pcg * 8];

#pragma unroll
        for (int i = 0; i < 4; i++)
#pragma unroll
            for (int j = 0; j < 4; j++)
                acc[i][j] = __builtin_amdgcn_mfma_f32_16x16x32_bf16(
                    af[i], bfx[j], acc[i][j], 0, 0, 0);
        __syncthreads();
    }

    // ---- epilogue transpose: D row = wn+i*16+4*fq+reg (reg=proj),
    //      col = wt+j*16+fr.  planes: 0=bx 1=cc 2=la
    const int hq = wn >> 2;                  // 0 or 16
#pragma unroll
    for (int i = 0; i < 4; i++) {
        const int hl = hq + i * 4 + fq;      // h_local 0..31
        const float ae = A_e[bn * 32 + hl];
#pragma unroll
        for (int j = 0; j < 4; j++) {
            const int tl = wt + j * 16 + fr;
            f32x4 v = acc[i][j];
            float sig = 1.0f / (1.0f + __expf(-v[3]));
            smem[(0 * 128 + tl) * 40 + hl] = f2bf(v[0] * v[1]);  // BX
            smem[(1 * 128 + tl) * 40 + hl] = f2bf(v[2]);         // CC
            smem[(2 * 128 + tl) * 40 + hl] = f2bf(sig * ae);     // LA
        }
    }
    __syncthreads();

    // ---- pass 1: per-(seg,h) totals
    const int hi  = tid & 31;
    const int seg = tid >> 5;
    {
        float p = 1.f, s = 0.f;
        const int tbase = seg * 16;
#pragma unroll
        for (int t = 0; t < 16; t++) {
            float a  = exp2f(bf2f(smem[(2 * 128 + tbase + t) * 40 + hi]));
            float bx = bf2f(smem[(0 * 128 + tbase + t) * 40 + hi]);
            s = fmaf(a, s, bx);
            p *= a;
        }
        Ps[seg * 32 + hi] = p;
        Ss[seg * 32 + hi] = s;
    }
    __syncthreads();

    // ---- seg-prefix in place; write chunk-level P,S
    if (tid < 32) {
        float rr = 1.f, sr = 0.f;
#pragma unroll
        for (int sg = 0; sg < 8; sg++) {
            float ps = Ps[sg * 32 + tid], ss = Ss[sg * 32 + tid];
            Ps[sg * 32 + tid] = rr;      // prefix product before seg
            Ss[sg * 32 + tid] = sr;      // local scan value at seg start
            sr = fmaf(ps, sr, ss);
            rr *= ps;
        }
        P[(size_t)bm * HID + bn * 32 + tid] = rr;
        S[(size_t)bm * HID + bn * 32 + tid] = sr;
    }
    __syncthreads();

    // ---- pass 2: emit yb = cc*h_local, yc = cc*r_local into planes 0/2
    {
        const float Rp = Ps[seg * 32 + hi];
        const float Sp = Ss[seg * 32 + hi];
        float r = 1.f, s = 0.f;
        const int tbase = seg * 16;
#pragma unroll
        for (int t = 0; t < 16; t++) {
            const int row = tbase + t;
            float a  = exp2f(bf2f(smem[(2 * 128 + row) * 40 + hi]));
            float bx = bf2f(smem[(0 * 128 + row) * 40 + hi]);
            float cc = bf2f(smem[(1 * 128 + row) * 40 + hi]);
            s = fmaf(a, s, bx);
            r *= a;
            float hl = fmaf(r, Sp, s);                        // local scan
            smem[(0 * 128 + row) * 40 + hi] = f2bf(cc * hl);       // yb
            smem[(2 * 128 + row) * 40 + hi] = f2bf(cc * r * Rp);   // yc
        }
    }
    __syncthreads();

    // ---- packed store-back of planes 0 (YB) and 2 (YC): 4 iters
#pragma unroll
    for (int it = 0; it < 4; it++) {
        const int g = it * 64 + (tid >> 2);
        const int a = g >> 7;             // 0 -> YB, 1 -> YC
        const int t = g & 127;
        const int c = tid & 3;
        uint4 vd = *(const uint4*)&smem[((a * 2) * 128 + t) * 40 + c * 8];
        u16* dst = (a == 0 ? YB : YC) +
                   (size_t)(m0t + t) * HID + bn * 32 + c * 8;
        *(uint4*)dst = vd;
    }
}

// ---------------------------------------------------------------------------
// Kernel 4: sequential combine across 64 chunks per channel -> H0[c,h]
// ---------------------------------------------------------------------------
__global__ void scan_combine(const float* __restrict__ P,
                             const float* __restrict__ S,
                             float* __restrict__ H0)
{
    const int h = blockIdx.x * 256 + threadIdx.x;
    float hrun = 0.f;
#pragma unroll 8
    for (int c = 0; c < NCH; c++) {
        H0[c * HID + h] = hrun;
        hrun = fmaf(P[c * HID + h], hrun, S[c * HID + h]);
    }
}

// ---------------------------------------------------------------------------
// Kernel 5: fully-parallel output: y[t,h] = YB + YC*h0[chunk(t),h], then
// MFMA out-projection, atomicAdd into out. Block = (64-t sub-chunk, hgroup
// of 256 h): 1024 blocks. No serial dependency anywhere.
// ---------------------------------------------------------------------------
__launch_bounds__(256)
__global__ void final_out(const u16* __restrict__ YB,
                          const u16* __restrict__ YC,
                          const float* __restrict__ H0,
                          const float* __restrict__ W_out,
                          float* __restrict__ out)
{
    __shared__ __align__(16) u16 ybuf[64 * 256];    // 32 KB
    __shared__ __align__(16) u16 wst[8 * 264];      // 4.2 KB
    __shared__ float h0s[256];
    const int tid  = threadIdx.x;
    const int tc   = blockIdx.x >> 3;    // 64-t sub-chunk, 0..127
    const int hg   = blockIdx.x & 7;
    const int lane = tid & 63;
    const int wave = tid >> 6;
    const int fr   = lane & 15;
    const int fq   = lane >> 4;
    const int t0   = tc * 64;

#pragma unroll
    for (int o = 0; o < 8; o++)
        wst[o * 264 + tid] = f2bf(W_out[(size_t)o * HID + hg * 256 + tid]);
    h0s[tid] = H0[(size_t)(tc >> 1) * HID + hg * 256 + tid];
    __syncthreads();

    // phase 1: y -> ybuf (XOR-swizzled col groups), 8 b128-load pairs/thread
    const int g   = tid & 31;            // h col-group (constant per thread)
    const int tb0 = tid >> 5;            // 0..7
    float4 h0a = *(const float4*)&h0s[g * 8];
    float4 h0b = *(const float4*)&h0s[g * 8 + 4];
    const float h0r[8] = { h0a.x, h0a.y, h0a.z, h0a.w,
                           h0b.x, h0b.y, h0b.z, h0b.w };
#pragma unroll
    for (int k = 0; k < 8; k++) {
        const int t = tb0 + k * 8;
        const size_t off = (size_t)(t0 + t) * HID + hg * 256 + g * 8;
        bf16x8 yb = *(const bf16x8*)(YB + off);
        bf16x8 yc = *(const bf16x8*)(YC + off);
        bf16x8 yv;
#pragma unroll
        for (int e = 0; e < 8; e++) {
            float y = fmaf(bf2f((u16)yc[e]), h0r[e], bf2f((u16)yb[e]));
            yv[e] = (short)f2bf(y);
        }
        *(bf16x8*)&ybuf[t * 256 + ((g ^ (t & 7)) << 3)] = yv;
    }
    __syncthreads();

    // W_out A-frags from LDS: lane fr = o (rows 8..15 zero), k = fq*8+j
    bf16x8 bw[8];
#pragma unroll
    for (int ks = 0; ks < 8; ks++) {
        bf16x8 w = {0, 0, 0, 0, 0, 0, 0, 0};
        if (fr < 8)
            w = *(const bf16x8*)&wst[fr * 264 + ks * 32 + fq * 8];
        bw[ks] = w;
    }

    // phase 2: one 16-t m-tile per wave; D row (4fq+reg) = o, col fr = t
    {
        const int t = wave * 16 + fr;
        f32x4 acc2 = {0.f, 0.f, 0.f, 0.f};
#pragma unroll
        for (int ks = 0; ks < 8; ks++) {
            const int gg = ks * 4 + fq;
            bf16x8 yv = *(const bf16x8*)
                &ybuf[t * 256 + ((gg ^ (fr & 7)) << 3)];
            acc2 = __builtin_amdgcn_mfma_f32_16x16x32_bf16(bw[ks], yv, acc2,
                                                           0, 0, 0);
        }
        if (fq < 2) {
            const int tg = t0 + t;
#pragma unroll
            for (int reg = 0; reg < 4; reg++)
                atomicAdd(&out[(size_t)tg * NOBJ + 4 * fq + reg], acc2[reg]);
        }
    }
}

// ---------------------------------------------------------------------------
extern "C" void kernel_launch(void* const* d_in, const int* in_sizes, int n_in,
                              void* d_out, int out_size, void* d_ws, size_t ws_size,
                              hipStream_t stream)
{
    const float* x      = (const float*)d_in[0];
    const float* Win    = (const float*)d_in[1];
    const float* WB     = (const float*)d_in[2];
    const float* WC     = (const float*)d_in[3];
    const float* Wd     = (const float*)d_in[4];
    const float* A_log  = (const float*)d_in[5];
    const float* W_out  = (const float*)d_in[6];
    const float* b_out  = (const float*)d_in[7];
    const float* W_skip = (const float*)d_in[8];
    float* out = (float*)d_out;

    char* ws = (char*)d_ws;
    size_t off = 0;
    auto alloc = [&](size_t bytes) -> void* {
        void* p = (void*)(ws + off);
        off += (bytes + 255) & ~(size_t)255;
        return p;
    };

    u16*   x_bf = (u16*)  alloc((size_t)TT * KOBS * 2);        //  8.4 MB
    u16*   W_bf = (u16*)  alloc((size_t)4 * HID * KOBS * 2);   //  8.4 MB
    float* A_e  = (float*)alloc((size_t)HID * 4);
    u16*   YB   = (u16*)  alloc((size_t)TT * HID * 2);         // 33.6 MB
    u16*   YC   = (u16*)  alloc((size_t)TT * HID * 2);         // 33.6 MB
    float* P    = (float*)alloc((size_t)NCH * HID * 4);        //  0.5 MB
    float* S    = (float*)alloc((size_t)NCH * HID * 4);        //  0.5 MB
    float* H0   = (float*)alloc((size_t)NCH * HID * 4);        //  0.5 MB
    (void)ws_size; (void)in_sizes; (void)n_in; (void)out_size;

    prep_w<<<2048, 256, 0, stream>>>(Win, WB, WC, Wd, A_log, W_bf, A_e);
    prep_x_out<<<512, 256, 0, stream>>>(x, b_out, W_skip, out, x_bf);
    gemm_fused<<<4096, 256, 0, stream>>>(x_bf, W_bf, A_e, YB, YC, P, S);
    scan_combine<<<8, 256, 0, stream>>>(P, S, H0);
    final_out<<<1024, 256, 0, stream>>>(YB, YC, H0, W_out, out);
}